// Round 1
// baseline (41.852 us; speedup 1.0000x reference)
//
#include <hip/hip_runtime.h>

#define IMG 512
#define HW (IMG * IMG)      // 262144
#define NB 257              // bins (L = 512/2 + 1)
#define BATCH 16

// Ring-bin index for pixel (h, w) of a 512x512 image.
// Matches: plane[0,:] = plane[:,0] = 256; interior = 255 - min(j,k,510-j,510-k), j=h-1,k=w-1.
__device__ __forceinline__ int bin_of(int h, int w) {
    if (h == 0 || w == 0) return 256;
    int j = h - 1, k = w - 1;
    int ring = min(min(j, k), min(510 - j, 510 - k));
    return 255 - ring;
}

__global__ __launch_bounds__(256) void hist_kernel(const float* __restrict__ x,
                                                   float* __restrict__ prof) {
    const int b = blockIdx.y;
    __shared__ float bins[NB];
    for (int i = threadIdx.x; i < NB; i += 256) bins[i] = 0.f;
    __syncthreads();

    const float* xr = x + (size_t)b * 3 * HW;
    const float* xg = xr + HW;
    const float* xb = xg + HW;

    // 65536 float4-quads per image; gridDim.x = 128 -> 512 quads/block, 2 per thread (strided for coalescing).
    const int qbase = blockIdx.x * 512;
#pragma unroll
    for (int it = 0; it < 2; ++it) {
        const int q = qbase + it * 256 + threadIdx.x;
        const int p = q << 2;                 // pixel index; 4 consecutive pixels, same row (512 % 4 == 0)
        const float4 r  = *reinterpret_cast<const float4*>(xr + p);
        const float4 g  = *reinterpret_cast<const float4*>(xg + p);
        const float4 bl = *reinterpret_cast<const float4*>(xb + p);

        const float m0 = 20.f * (0.299f * r.x + 0.587f * g.x + 0.114f * bl.x);
        const float m1 = 20.f * (0.299f * r.y + 0.587f * g.y + 0.114f * bl.y);
        const float m2 = 20.f * (0.299f * r.z + 0.587f * g.z + 0.114f * bl.z);
        const float m3 = 20.f * (0.299f * r.w + 0.587f * g.w + 0.114f * bl.w);

        const int h = p >> 9;
        const int w = p & 511;
        const int b0 = bin_of(h, w);
        const int b1 = bin_of(h, w + 1);
        const int b2 = bin_of(h, w + 2);
        const int b3 = bin_of(h, w + 3);

        // run-merge consecutive same-bin pixels -> usually a single LDS atomic
        float s = m0;
        int cur = b0;
        if (b1 == cur) { s += m1; } else { atomicAdd(&bins[cur], s); cur = b1; s = m1; }
        if (b2 == cur) { s += m2; } else { atomicAdd(&bins[cur], s); cur = b2; s = m2; }
        if (b3 == cur) { s += m3; } else { atomicAdd(&bins[cur], s); cur = b3; s = m3; }
        atomicAdd(&bins[cur], s);
    }
    __syncthreads();

    float* pb = prof + (size_t)b * NB;
    for (int i = threadIdx.x; i < NB; i += 256) {
        const float v = bins[i];
        if (v != 0.f) atomicAdd(&pb[i], v);
    }
}

__global__ __launch_bounds__(256) void finalize_kernel(const float* __restrict__ prof,
                                                       const float* __restrict__ mask_n,
                                                       float* __restrict__ out) {
    __shared__ float smin[256];
    __shared__ float smax[256];
    float lmin = 3.402823466e+38f, lmax = -3.402823466e+38f;
    for (int i = threadIdx.x; i < BATCH * NB; i += 256) {
        const float v = prof[i] / mask_n[i % NB];
        lmin = fminf(lmin, v);
        lmax = fmaxf(lmax, v);
    }
    smin[threadIdx.x] = lmin;
    smax[threadIdx.x] = lmax;
    __syncthreads();
    for (int s = 128; s > 0; s >>= 1) {
        if (threadIdx.x < s) {
            smin[threadIdx.x] = fminf(smin[threadIdx.x], smin[threadIdx.x + s]);
            smax[threadIdx.x] = fmaxf(smax[threadIdx.x], smax[threadIdx.x + s]);
        }
        __syncthreads();
    }
    const float pmin = smin[0];
    const float inv = 1.f / (smax[0] - pmin);
    for (int i = threadIdx.x; i < BATCH * NB; i += 256) {
        const float v = prof[i] / mask_n[i % NB];
        out[i] = (v - pmin) * inv;
    }
}

extern "C" void kernel_launch(void* const* d_in, const int* in_sizes, int n_in,
                              void* d_out, int out_size, void* d_ws, size_t ws_size,
                              hipStream_t stream) {
    const float* x      = (const float*)d_in[0];   // [16,3,512,512] f32
    const float* mask_n = (const float*)d_in[2];   // [257] f32 (mask d_in[1] unused — bins computed analytically)
    float* out  = (float*)d_out;                   // [16,257] f32
    float* prof = (float*)d_ws;                    // [16,257] f32 accumulator

    hipMemsetAsync(prof, 0, (size_t)BATCH * NB * sizeof(float), stream);
    hist_kernel<<<dim3(128, BATCH), 256, 0, stream>>>(x, prof);
    finalize_kernel<<<1, 256, 0, stream>>>(prof, mask_n, out);
}